// Round 9
// baseline (446.883 us; speedup 1.0000x reference)
//
#include <hip/hip_runtime.h>
#include <math.h>

// CALIBRATION ROUND: R7 pipeline, but scan_kernel runs its full pass TWICE
// (second pass on partner row i^4096 -> scratch) to (a) measure S via total
// delta and (b) push the scan above the 160-us harness fills into the rocprof
// top-5 so we finally see its FETCH_SIZE / hbm_gbps / VALUBusy directly.
//
// Problem: N=8192 nodes, D=256 features, H=64 hidden.
// out = [h_out (N*D floats), e (N floats)] concatenated, fp32.
// ws: g (4 MB) | idx (4 MB) | cnt (32 KB) | idx2 scratch (4 MB) | cnt2 (32 KB)

typedef float nfloat4 __attribute__((ext_vector_type(4)));

__device__ inline float bf16_to_f32(unsigned short s) {
    union { unsigned u; float f; } c; c.u = ((unsigned)s) << 16; return c.f;
}
__device__ inline unsigned short f32_to_bf16(float f) {   // RNE, finite inputs
    union { float f; unsigned u; } c; c.f = f;
    unsigned r = c.u + 0x7FFFu + ((c.u >> 16) & 1u);
    return (unsigned short)(r >> 16);
}

// ---------------- Kernel 1: gate + bf16 pre-scale ----------------------------
__global__ __launch_bounds__(256) void gate_kernel(const float* __restrict__ h,
                                                   const float* __restrict__ W1,
                                                   const float* __restrict__ b1,
                                                   const float* __restrict__ W2,
                                                   const float* __restrict__ b2,
                                                   float* __restrict__ e_out,
                                                   unsigned short* __restrict__ g_out,
                                                   int N) {
    __shared__ float W1s[256 * 64];            // 64 KB
    const int tid = threadIdx.x;

    const float4* W1v = reinterpret_cast<const float4*>(W1);
    float4* W1sv = reinterpret_cast<float4*>(W1s);
    #pragma unroll
    for (int t = 0; t < 16; ++t) W1sv[tid + 256 * t] = W1v[tid + 256 * t];
    __syncthreads();

    const int wave = tid >> 6;
    const int k    = tid & 63;
    const float b1k = b1[k];
    const float w2k = W2[k];
    const float b2v = b2[0];

    const int base = blockIdx.x * 16;
    for (int r = wave; r < 16; r += 4) {
        const int i = base + r;
        if (i >= N) break;
        const float4* hv = reinterpret_cast<const float4*>(h + (size_t)i * 256);
        float acc = 0.f;
        #pragma unroll 4
        for (int d4 = 0; d4 < 64; ++d4) {
            float4 a = hv[d4];
            const int d = d4 * 4;
            acc = fmaf(a.x, W1s[(d + 0) * 64 + k], acc);
            acc = fmaf(a.y, W1s[(d + 1) * 64 + k], acc);
            acc = fmaf(a.z, W1s[(d + 2) * 64 + k], acc);
            acc = fmaf(a.w, W1s[(d + 3) * 64 + k], acc);
        }
        float v = fmaxf(acc + b1k, 0.f) * w2k;
        #pragma unroll
        for (int off = 32; off > 0; off >>= 1) v += __shfl_down(v, off);
        float vs = __shfl(v, 0);
        float ev = 1.f / (1.f + expf(-(vs + b2v)));
        if (k == 0) e_out[i] = ev;
        float4 hr = hv[k];
        ushort4 p;
        p.x = f32_to_bf16(ev * hr.x);
        p.y = f32_to_bf16(ev * hr.y);
        p.z = f32_to_bf16(ev * hr.z);
        p.w = f32_to_bf16(ev * hr.w);
        reinterpret_cast<ushort4*>(g_out + (size_t)i * 256)[k] = p;
    }
}

// ---------------- Kernel 2a: A-scan -> per-row column lists (DOUBLED) --------
// Pass 0: real row i -> idx/cnt (consumed by gather).  Pass 1: partner row
// i^(N/2) -> idx2/cnt2 scratch (identical work, measurement only).
__global__ __launch_bounds__(256) void scan_kernel(const float* __restrict__ A,
                                                   unsigned short* __restrict__ idx,
                                                   int* __restrict__ cnt,
                                                   unsigned short* __restrict__ idx2,
                                                   int* __restrict__ cnt2,
                                                   int N) {
    const int tid  = threadIdx.x;
    const int lane = tid & 63;
    const int wrow = blockIdx.x * 4 + (tid >> 6);
    if (wrow >= N) return;

    const unsigned long long below = (lane == 63) ? ~0ull >> 1
                                                  : (1ull << lane) - 1;
    const int groups = N / 256;                 // 32, multiple of 4

    #pragma unroll 1
    for (int rep = 0; rep < 2; ++rep) {
        const int i = (rep == 0) ? wrow : (wrow ^ (N >> 1));
        const nfloat4* Arow = reinterpret_cast<const nfloat4*>(A + (size_t)i * N);
        unsigned short* rb = ((rep == 0) ? idx : idx2) + (size_t)i * 256;

        nfloat4 q0 = __builtin_nontemporal_load(&Arow[0 * 64 + lane]);
        nfloat4 q1 = __builtin_nontemporal_load(&Arow[1 * 64 + lane]);
        nfloat4 q2 = __builtin_nontemporal_load(&Arow[2 * 64 + lane]);
        nfloat4 q3 = __builtin_nontemporal_load(&Arow[3 * 64 + lane]);

        int count = 0;                          // wave-uniform
        for (int gi = 0; gi < groups; gi += 4) {
            nfloat4 c0 = q0, c1 = q1, c2 = q2, c3 = q3;
            if (gi + 4 < groups) {
                q0 = __builtin_nontemporal_load(&Arow[(gi + 4) * 64 + lane]);
                q1 = __builtin_nontemporal_load(&Arow[(gi + 5) * 64 + lane]);
                q2 = __builtin_nontemporal_load(&Arow[(gi + 6) * 64 + lane]);
                q3 = __builtin_nontemporal_load(&Arow[(gi + 7) * 64 + lane]);
            }
            #pragma unroll
            for (int u = 0; u < 4; ++u) {
                nfloat4 a4 = (u == 0) ? c0 : (u == 1) ? c1 : (u == 2) ? c2 : c3;
                const int colbase = (gi + u) * 256 + 4 * lane;
                #pragma unroll
                for (int s = 0; s < 4; ++s) {
                    float av = (s == 0) ? a4.x : (s == 1) ? a4.y
                             : (s == 2) ? a4.z : a4.w;
                    unsigned long long m = __ballot(av > 0.f);
                    if (av > 0.f) {
                        int pos = count + __popcll(m & below);
                        if (pos < 256) rb[pos] = (unsigned short)(colbase + s);
                    }
                    count += __popcll(m);
                }
            }
        }
        if (lane == 0) ((rep == 0) ? cnt : cnt2)[i] = (count < 256) ? count : 256;
    }
}

// ---------------- Kernel 2b: gather h_out[i,:] = sum g[idx[i,p],:] -----------
__global__ __launch_bounds__(256) void gather_kernel(const unsigned short* __restrict__ idx,
                                                     const int* __restrict__ cnt,
                                                     const unsigned short* __restrict__ g,
                                                     float* __restrict__ h_out,
                                                     int N) {
    const int tid  = threadIdx.x;
    const int lane = tid & 63;
    const int i    = blockIdx.x * 4 + (tid >> 6);
    if (i >= N) return;

    const int c = cnt[i];
    const ushort4* gv  = reinterpret_cast<const ushort4*>(g);
    const unsigned short* rb = idx + (size_t)i * 256;
    const uint4* rbw = reinterpret_cast<const uint4*>(rb);

    float4 acc = {0.f, 0.f, 0.f, 0.f};
    int p = 0;
    uint4 iw = (c >= 8) ? rbw[0] : make_uint4(0, 0, 0, 0);
    for (; p + 8 <= c; p += 8) {
        uint4 iw_next;
        if (p + 16 <= c) iw_next = rbw[(p >> 3) + 1];
        const int j0 = iw.x & 0xFFFF, j1 = iw.x >> 16;
        const int j2 = iw.y & 0xFFFF, j3 = iw.y >> 16;
        const int j4 = iw.z & 0xFFFF, j5 = iw.z >> 16;
        const int j6 = iw.w & 0xFFFF, j7 = iw.w >> 16;
        ushort4 g0 = gv[(size_t)j0 * 64 + lane];
        ushort4 g1 = gv[(size_t)j1 * 64 + lane];
        ushort4 g2 = gv[(size_t)j2 * 64 + lane];
        ushort4 g3 = gv[(size_t)j3 * 64 + lane];
        ushort4 g4 = gv[(size_t)j4 * 64 + lane];
        ushort4 g5 = gv[(size_t)j5 * 64 + lane];
        ushort4 g6 = gv[(size_t)j6 * 64 + lane];
        ushort4 g7 = gv[(size_t)j7 * 64 + lane];
        acc.x += bf16_to_f32(g0.x); acc.y += bf16_to_f32(g0.y); acc.z += bf16_to_f32(g0.z); acc.w += bf16_to_f32(g0.w);
        acc.x += bf16_to_f32(g1.x); acc.y += bf16_to_f32(g1.y); acc.z += bf16_to_f32(g1.z); acc.w += bf16_to_f32(g1.w);
        acc.x += bf16_to_f32(g2.x); acc.y += bf16_to_f32(g2.y); acc.z += bf16_to_f32(g2.z); acc.w += bf16_to_f32(g2.w);
        acc.x += bf16_to_f32(g3.x); acc.y += bf16_to_f32(g3.y); acc.z += bf16_to_f32(g3.z); acc.w += bf16_to_f32(g3.w);
        acc.x += bf16_to_f32(g4.x); acc.y += bf16_to_f32(g4.y); acc.z += bf16_to_f32(g4.z); acc.w += bf16_to_f32(g4.w);
        acc.x += bf16_to_f32(g5.x); acc.y += bf16_to_f32(g5.y); acc.z += bf16_to_f32(g5.z); acc.w += bf16_to_f32(g5.w);
        acc.x += bf16_to_f32(g6.x); acc.y += bf16_to_f32(g6.y); acc.z += bf16_to_f32(g6.z); acc.w += bf16_to_f32(g6.w);
        acc.x += bf16_to_f32(g7.x); acc.y += bf16_to_f32(g7.y); acc.z += bf16_to_f32(g7.z); acc.w += bf16_to_f32(g7.w);
        iw = iw_next;
    }
    for (; p < c; ++p) {
        int j = rb[p];
        ushort4 gj = gv[(size_t)j * 64 + lane];
        acc.x += bf16_to_f32(gj.x); acc.y += bf16_to_f32(gj.y);
        acc.z += bf16_to_f32(gj.z); acc.w += bf16_to_f32(gj.w);
    }

    nfloat4 r; r.x = acc.x; r.y = acc.y; r.z = acc.z; r.w = acc.w;
    nfloat4* outv = reinterpret_cast<nfloat4*>(h_out + (size_t)i * 256);
    __builtin_nontemporal_store(r, &outv[lane]);
}

extern "C" void kernel_launch(void* const* d_in, const int* in_sizes, int n_in,
                              void* d_out, int out_size, void* d_ws, size_t ws_size,
                              hipStream_t stream) {
    const float* A  = (const float*)d_in[0];   // [N, N]
    const float* h  = (const float*)d_in[1];   // [N, D]
    const float* W1 = (const float*)d_in[2];   // [D, H]
    const float* b1 = (const float*)d_in[3];   // [H]
    const float* W2 = (const float*)d_in[4];   // [H, 1]
    const float* b2 = (const float*)d_in[5];   // [1]

    const int H = in_sizes[3];                 // 64
    const int D = in_sizes[2] / H;             // 256
    const int N = in_sizes[1] / D;             // 8192

    float* out   = (float*)d_out;
    float* h_out = out;                        // N*D
    float* e_out = out + (size_t)N * D;        // N

    unsigned char* ws = (unsigned char*)d_ws;
    unsigned short* g_buf    = (unsigned short*)ws;                          // 4 MB
    unsigned short* idx_buf  = (unsigned short*)(ws + (size_t)N * D * 2);    // 4 MB
    int*            cnt_buf  = (int*)(ws + (size_t)N * D * 4);               // 32 KB
    unsigned short* idx2_buf = (unsigned short*)(ws + (size_t)N * D * 4 + N * 4);
    int*            cnt2_buf = (int*)(ws + (size_t)N * D * 6 + N * 4);

    scan_kernel<<<(N + 3) / 4, 256, 0, stream>>>(A, idx_buf, cnt_buf,
                                                 idx2_buf, cnt2_buf, N);
    gate_kernel<<<(N + 15) / 16, 256, 0, stream>>>(h, W1, b1, W2, b2, e_out, g_buf, N);
    gather_kernel<<<(N + 3) / 4, 256, 0, stream>>>(idx_buf, cnt_buf, g_buf, h_out, N);
}

// Round 10
// 427.793 us; speedup vs baseline: 1.0446x; 1.0446x over previous
//
#include <hip/hip_runtime.h>
#include <math.h>

// CALIBRATION ROUND 2: R7 pipeline, but gather_kernel runs its full pass TWICE
// (second pass on partner row i^4096 -> ws scratch, NT-stored) to (a) measure
// gather time G via total delta vs R7's 402.5 us and (b) push the gather above
// the 160-us harness fills into the rocprof top-5 for direct counters.
//
// Problem: N=8192 nodes, D=256 features, H=64 hidden.
// out = [h_out (N*D floats), e (N floats)] concatenated, fp32.
// ws: g (4 MB) | idx (4 MB) | cnt (32 KB) | scratch_out (8 MB)

typedef float nfloat4 __attribute__((ext_vector_type(4)));

__device__ inline float bf16_to_f32(unsigned short s) {
    union { unsigned u; float f; } c; c.u = ((unsigned)s) << 16; return c.f;
}
__device__ inline unsigned short f32_to_bf16(float f) {   // RNE, finite inputs
    union { float f; unsigned u; } c; c.f = f;
    unsigned r = c.u + 0x7FFFu + ((c.u >> 16) & 1u);
    return (unsigned short)(r >> 16);
}

// ---------------- Kernel 1: gate + bf16 pre-scale ----------------------------
__global__ __launch_bounds__(256) void gate_kernel(const float* __restrict__ h,
                                                   const float* __restrict__ W1,
                                                   const float* __restrict__ b1,
                                                   const float* __restrict__ W2,
                                                   const float* __restrict__ b2,
                                                   float* __restrict__ e_out,
                                                   unsigned short* __restrict__ g_out,
                                                   int N) {
    __shared__ float W1s[256 * 64];            // 64 KB
    const int tid = threadIdx.x;

    const float4* W1v = reinterpret_cast<const float4*>(W1);
    float4* W1sv = reinterpret_cast<float4*>(W1s);
    #pragma unroll
    for (int t = 0; t < 16; ++t) W1sv[tid + 256 * t] = W1v[tid + 256 * t];
    __syncthreads();

    const int wave = tid >> 6;
    const int k    = tid & 63;
    const float b1k = b1[k];
    const float w2k = W2[k];
    const float b2v = b2[0];

    const int base = blockIdx.x * 16;
    for (int r = wave; r < 16; r += 4) {
        const int i = base + r;
        if (i >= N) break;
        const float4* hv = reinterpret_cast<const float4*>(h + (size_t)i * 256);
        float acc = 0.f;
        #pragma unroll 4
        for (int d4 = 0; d4 < 64; ++d4) {
            float4 a = hv[d4];
            const int d = d4 * 4;
            acc = fmaf(a.x, W1s[(d + 0) * 64 + k], acc);
            acc = fmaf(a.y, W1s[(d + 1) * 64 + k], acc);
            acc = fmaf(a.z, W1s[(d + 2) * 64 + k], acc);
            acc = fmaf(a.w, W1s[(d + 3) * 64 + k], acc);
        }
        float v = fmaxf(acc + b1k, 0.f) * w2k;
        #pragma unroll
        for (int off = 32; off > 0; off >>= 1) v += __shfl_down(v, off);
        float vs = __shfl(v, 0);
        float ev = 1.f / (1.f + expf(-(vs + b2v)));
        if (k == 0) e_out[i] = ev;
        float4 hr = hv[k];
        ushort4 p;
        p.x = f32_to_bf16(ev * hr.x);
        p.y = f32_to_bf16(ev * hr.y);
        p.z = f32_to_bf16(ev * hr.z);
        p.w = f32_to_bf16(ev * hr.w);
        reinterpret_cast<ushort4*>(g_out + (size_t)i * 256)[k] = p;
    }
}

// ---------------- Kernel 2a: A-scan -> per-row column lists ------------------
// Wave per row, prefetch depth 4 NT loads; ballot + prefix-popcount compaction.
// Measured R9: ~44 us single pass = HBM roofline for the 256 MB A stream.
__global__ __launch_bounds__(256) void scan_kernel(const float* __restrict__ A,
                                                   unsigned short* __restrict__ idx,
                                                   int* __restrict__ cnt,
                                                   int N) {
    const int tid  = threadIdx.x;
    const int lane = tid & 63;
    const int i    = blockIdx.x * 4 + (tid >> 6);
    if (i >= N) return;

    const nfloat4* Arow = reinterpret_cast<const nfloat4*>(A + (size_t)i * N);
    unsigned short* rb = idx + (size_t)i * 256;
    const unsigned long long below = (lane == 63) ? ~0ull >> 1
                                                  : (1ull << lane) - 1;

    const int groups = N / 256;                 // 32, multiple of 4
    nfloat4 q0 = __builtin_nontemporal_load(&Arow[0 * 64 + lane]);
    nfloat4 q1 = __builtin_nontemporal_load(&Arow[1 * 64 + lane]);
    nfloat4 q2 = __builtin_nontemporal_load(&Arow[2 * 64 + lane]);
    nfloat4 q3 = __builtin_nontemporal_load(&Arow[3 * 64 + lane]);

    int count = 0;                              // wave-uniform
    for (int gi = 0; gi < groups; gi += 4) {
        nfloat4 c0 = q0, c1 = q1, c2 = q2, c3 = q3;
        if (gi + 4 < groups) {
            q0 = __builtin_nontemporal_load(&Arow[(gi + 4) * 64 + lane]);
            q1 = __builtin_nontemporal_load(&Arow[(gi + 5) * 64 + lane]);
            q2 = __builtin_nontemporal_load(&Arow[(gi + 6) * 64 + lane]);
            q3 = __builtin_nontemporal_load(&Arow[(gi + 7) * 64 + lane]);
        }
        #pragma unroll
        for (int u = 0; u < 4; ++u) {
            nfloat4 a4 = (u == 0) ? c0 : (u == 1) ? c1 : (u == 2) ? c2 : c3;
            const int colbase = (gi + u) * 256 + 4 * lane;
            #pragma unroll
            for (int s = 0; s < 4; ++s) {
                float av = (s == 0) ? a4.x : (s == 1) ? a4.y : (s == 2) ? a4.z : a4.w;
                unsigned long long m = __ballot(av > 0.f);
                if (av > 0.f) {
                    int pos = count + __popcll(m & below);
                    if (pos < 256) rb[pos] = (unsigned short)(colbase + s);
                }
                count += __popcll(m);
            }
        }
    }
    if (lane == 0) cnt[i] = (count < 256) ? count : 256;
}

// ---------------- Kernel 2b: gather (DOUBLED for calibration) ----------------
// Pass 0: real row i -> h_out.  Pass 1: partner row i^(N/2) -> ws scratch
// (identical work + access statistics, measurement only).
__global__ __launch_bounds__(256) void gather_kernel(const unsigned short* __restrict__ idx,
                                                     const int* __restrict__ cnt,
                                                     const unsigned short* __restrict__ g,
                                                     float* __restrict__ h_out,
                                                     float* __restrict__ scratch,
                                                     int N) {
    const int tid  = threadIdx.x;
    const int lane = tid & 63;
    const int wrow = blockIdx.x * 4 + (tid >> 6);
    if (wrow >= N) return;

    const ushort4* gv = reinterpret_cast<const ushort4*>(g);

    #pragma unroll 1
    for (int rep = 0; rep < 2; ++rep) {
        const int i = (rep == 0) ? wrow : (wrow ^ (N >> 1));
        const int c = cnt[i];
        const unsigned short* rb = idx + (size_t)i * 256;
        const uint4* rbw = reinterpret_cast<const uint4*>(rb);

        float4 acc = {0.f, 0.f, 0.f, 0.f};
        int p = 0;
        uint4 iw = (c >= 8) ? rbw[0] : make_uint4(0, 0, 0, 0);
        for (; p + 8 <= c; p += 8) {
            uint4 iw_next;
            if (p + 16 <= c) iw_next = rbw[(p >> 3) + 1];
            const int j0 = iw.x & 0xFFFF, j1 = iw.x >> 16;
            const int j2 = iw.y & 0xFFFF, j3 = iw.y >> 16;
            const int j4 = iw.z & 0xFFFF, j5 = iw.z >> 16;
            const int j6 = iw.w & 0xFFFF, j7 = iw.w >> 16;
            ushort4 g0 = gv[(size_t)j0 * 64 + lane];
            ushort4 g1 = gv[(size_t)j1 * 64 + lane];
            ushort4 g2 = gv[(size_t)j2 * 64 + lane];
            ushort4 g3 = gv[(size_t)j3 * 64 + lane];
            ushort4 g4 = gv[(size_t)j4 * 64 + lane];
            ushort4 g5 = gv[(size_t)j5 * 64 + lane];
            ushort4 g6 = gv[(size_t)j6 * 64 + lane];
            ushort4 g7 = gv[(size_t)j7 * 64 + lane];
            acc.x += bf16_to_f32(g0.x); acc.y += bf16_to_f32(g0.y); acc.z += bf16_to_f32(g0.z); acc.w += bf16_to_f32(g0.w);
            acc.x += bf16_to_f32(g1.x); acc.y += bf16_to_f32(g1.y); acc.z += bf16_to_f32(g1.z); acc.w += bf16_to_f32(g1.w);
            acc.x += bf16_to_f32(g2.x); acc.y += bf16_to_f32(g2.y); acc.z += bf16_to_f32(g2.z); acc.w += bf16_to_f32(g2.w);
            acc.x += bf16_to_f32(g3.x); acc.y += bf16_to_f32(g3.y); acc.z += bf16_to_f32(g3.z); acc.w += bf16_to_f32(g3.w);
            acc.x += bf16_to_f32(g4.x); acc.y += bf16_to_f32(g4.y); acc.z += bf16_to_f32(g4.z); acc.w += bf16_to_f32(g4.w);
            acc.x += bf16_to_f32(g5.x); acc.y += bf16_to_f32(g5.y); acc.z += bf16_to_f32(g5.z); acc.w += bf16_to_f32(g5.w);
            acc.x += bf16_to_f32(g6.x); acc.y += bf16_to_f32(g6.y); acc.z += bf16_to_f32(g6.z); acc.w += bf16_to_f32(g6.w);
            acc.x += bf16_to_f32(g7.x); acc.y += bf16_to_f32(g7.y); acc.z += bf16_to_f32(g7.z); acc.w += bf16_to_f32(g7.w);
            iw = iw_next;
        }
        for (; p < c; ++p) {
            int j = rb[p];
            ushort4 gj = gv[(size_t)j * 64 + lane];
            acc.x += bf16_to_f32(gj.x); acc.y += bf16_to_f32(gj.y);
            acc.z += bf16_to_f32(gj.z); acc.w += bf16_to_f32(gj.w);
        }

        nfloat4 r; r.x = acc.x; r.y = acc.y; r.z = acc.z; r.w = acc.w;
        float* dst = (rep == 0) ? h_out : scratch;
        nfloat4* outv = reinterpret_cast<nfloat4*>(dst + (size_t)i * 256);
        __builtin_nontemporal_store(r, &outv[lane]);
    }
}

extern "C" void kernel_launch(void* const* d_in, const int* in_sizes, int n_in,
                              void* d_out, int out_size, void* d_ws, size_t ws_size,
                              hipStream_t stream) {
    const float* A  = (const float*)d_in[0];   // [N, N]
    const float* h  = (const float*)d_in[1];   // [N, D]
    const float* W1 = (const float*)d_in[2];   // [D, H]
    const float* b1 = (const float*)d_in[3];   // [H]
    const float* W2 = (const float*)d_in[4];   // [H, 1]
    const float* b2 = (const float*)d_in[5];   // [1]

    const int H = in_sizes[3];                 // 64
    const int D = in_sizes[2] / H;             // 256
    const int N = in_sizes[1] / D;             // 8192

    float* out   = (float*)d_out;
    float* h_out = out;                        // N*D
    float* e_out = out + (size_t)N * D;        // N

    unsigned char* ws = (unsigned char*)d_ws;
    unsigned short* g_buf   = (unsigned short*)ws;                         // 4 MB
    unsigned short* idx_buf = (unsigned short*)(ws + (size_t)N * D * 2);   // 4 MB
    int*            cnt_buf = (int*)(ws + (size_t)N * D * 4);              // 32 KB
    float*          scratch = (float*)(ws + (size_t)N * D * 4 + 65536);    // 8 MB

    scan_kernel<<<(N + 3) / 4, 256, 0, stream>>>(A, idx_buf, cnt_buf, N);
    gate_kernel<<<(N + 15) / 16, 256, 0, stream>>>(h, W1, b1, W2, b2, e_out, g_buf, N);
    gather_kernel<<<(N + 3) / 4, 256, 0, stream>>>(idx_buf, cnt_buf, g_buf, h_out,
                                                   scratch, N);
}

// Round 11
// 417.890 us; speedup vs baseline: 1.0694x; 1.0237x over previous
//
#include <hip/hip_runtime.h>
#include <math.h>

// Problem: N=8192 nodes, D=256 features, H=64 hidden.
// out = [h_out (N*D floats), e (N floats)] concatenated, fp32.
// ws: g (N*256 bf16 = 4 MB) | idx (N*256 u16 = 4 MB) | cnt (N int)
//
// Measured decomposition (R9/R10 differential calibration): scan ~44 us
// (5.8 TB/s, HBM roofline), gather ~25 us, gate ~10 us; remaining ~322 us of
// dur_us is harness re-poison/restore (fixed).

typedef float nfloat4 __attribute__((ext_vector_type(4)));

__device__ inline float bf16_to_f32(unsigned short s) {
    union { unsigned u; float f; } c; c.u = ((unsigned)s) << 16; return c.f;
}
__device__ inline unsigned short f32_to_bf16(float f) {   // RNE, finite inputs
    union { float f; unsigned u; } c; c.f = f;
    unsigned r = c.u + 0x7FFFu + ((c.u >> 16) & 1u);
    return (unsigned short)(r >> 16);
}

// ---------------- Kernel 1: gate + bf16 pre-scale ----------------------------
// 256 blocks x 32 rows: W1 LDS staging (64 KB) amortized over 32 rows.
__global__ __launch_bounds__(256) void gate_kernel(const float* __restrict__ h,
                                                   const float* __restrict__ W1,
                                                   const float* __restrict__ b1,
                                                   const float* __restrict__ W2,
                                                   const float* __restrict__ b2,
                                                   float* __restrict__ e_out,
                                                   unsigned short* __restrict__ g_out,
                                                   int N) {
    __shared__ float W1s[256 * 64];            // 64 KB
    const int tid = threadIdx.x;

    const float4* W1v = reinterpret_cast<const float4*>(W1);
    float4* W1sv = reinterpret_cast<float4*>(W1s);
    #pragma unroll
    for (int t = 0; t < 16; ++t) W1sv[tid + 256 * t] = W1v[tid + 256 * t];
    __syncthreads();

    const int wave = tid >> 6;
    const int k    = tid & 63;
    const float b1k = b1[k];
    const float w2k = W2[k];
    const float b2v = b2[0];

    const int base = blockIdx.x * 32;
    for (int r = wave; r < 32; r += 4) {
        const int i = base + r;
        if (i >= N) break;
        const float4* hv = reinterpret_cast<const float4*>(h + (size_t)i * 256);
        float acc = 0.f;
        #pragma unroll 4
        for (int d4 = 0; d4 < 64; ++d4) {
            float4 a = hv[d4];                 // wave-uniform broadcast load
            const int d = d4 * 4;
            acc = fmaf(a.x, W1s[(d + 0) * 64 + k], acc);
            acc = fmaf(a.y, W1s[(d + 1) * 64 + k], acc);
            acc = fmaf(a.z, W1s[(d + 2) * 64 + k], acc);
            acc = fmaf(a.w, W1s[(d + 3) * 64 + k], acc);
        }
        float v = fmaxf(acc + b1k, 0.f) * w2k;
        #pragma unroll
        for (int off = 32; off > 0; off >>= 1) v += __shfl_down(v, off);
        float vs = __shfl(v, 0);
        float ev = 1.f / (1.f + expf(-(vs + b2v)));
        if (k == 0) e_out[i] = ev;
        float4 hr = hv[k];
        ushort4 p;
        p.x = f32_to_bf16(ev * hr.x);
        p.y = f32_to_bf16(ev * hr.y);
        p.z = f32_to_bf16(ev * hr.z);
        p.w = f32_to_bf16(ev * hr.w);
        reinterpret_cast<ushort4*>(g_out + (size_t)i * 256)[k] = p;
    }
}

// ---------------- Kernel 2a: A-scan -> per-row column lists ------------------
// Wave per row, prefetch depth 4 NT loads; ballot + prefix-popcount compaction.
// Measured: ~44 us = HBM roofline for the 256 MB A stream. Do not touch.
__global__ __launch_bounds__(256) void scan_kernel(const float* __restrict__ A,
                                                   unsigned short* __restrict__ idx,
                                                   int* __restrict__ cnt,
                                                   int N) {
    const int tid  = threadIdx.x;
    const int lane = tid & 63;
    const int i    = blockIdx.x * 4 + (tid >> 6);
    if (i >= N) return;

    const nfloat4* Arow = reinterpret_cast<const nfloat4*>(A + (size_t)i * N);
    unsigned short* rb = idx + (size_t)i * 256;
    const unsigned long long below = (lane == 63) ? ~0ull >> 1
                                                  : (1ull << lane) - 1;

    const int groups = N / 256;                 // 32, multiple of 4
    nfloat4 q0 = __builtin_nontemporal_load(&Arow[0 * 64 + lane]);
    nfloat4 q1 = __builtin_nontemporal_load(&Arow[1 * 64 + lane]);
    nfloat4 q2 = __builtin_nontemporal_load(&Arow[2 * 64 + lane]);
    nfloat4 q3 = __builtin_nontemporal_load(&Arow[3 * 64 + lane]);

    int count = 0;                              // wave-uniform
    for (int gi = 0; gi < groups; gi += 4) {
        nfloat4 c0 = q0, c1 = q1, c2 = q2, c3 = q3;
        if (gi + 4 < groups) {
            q0 = __builtin_nontemporal_load(&Arow[(gi + 4) * 64 + lane]);
            q1 = __builtin_nontemporal_load(&Arow[(gi + 5) * 64 + lane]);
            q2 = __builtin_nontemporal_load(&Arow[(gi + 6) * 64 + lane]);
            q3 = __builtin_nontemporal_load(&Arow[(gi + 7) * 64 + lane]);
        }
        #pragma unroll
        for (int u = 0; u < 4; ++u) {
            nfloat4 a4 = (u == 0) ? c0 : (u == 1) ? c1 : (u == 2) ? c2 : c3;
            const int colbase = (gi + u) * 256 + 4 * lane;
            #pragma unroll
            for (int s = 0; s < 4; ++s) {
                float av = (s == 0) ? a4.x : (s == 1) ? a4.y : (s == 2) ? a4.z : a4.w;
                unsigned long long m = __ballot(av > 0.f);
                if (av > 0.f) {
                    int pos = count + __popcll(m & below);
                    if (pos < 256) rb[pos] = (unsigned short)(colbase + s);
                }
                count += __popcll(m);
            }
        }
    }
    if (lane == 0) cnt[i] = (count < 256) ? count : 256;
}

// ---------------- Kernel 2b: paired-row gather -------------------------------
// Wave per output row. Each 16 B/lane uint4 load fetches TWO g-rows at once:
// lanes 0-31 read row j_even, lanes 32-63 read row j_odd (32 lanes x 16 B =
// one 512 B row each). Lane (half,fl) accumulates features 8*fl..8*fl+7 of its
// half's rows; final __shfl_xor(32) exchange-add merges halves. Halves the
// gather instruction count vs 8 B/lane single-row loads.
__global__ __launch_bounds__(256) void gather_kernel(const unsigned short* __restrict__ idx,
                                                     const int* __restrict__ cnt,
                                                     const unsigned short* __restrict__ g,
                                                     float* __restrict__ h_out,
                                                     int N) {
    const int tid  = threadIdx.x;
    const int lane = tid & 63;
    const int half = lane >> 5;                 // 0: even-index rows, 1: odd
    const int fl   = lane & 31;                 // feature block: 8*fl..8*fl+7
    const int i    = blockIdx.x * 4 + (tid >> 6);
    if (i >= N) return;

    const int c = cnt[i];
    const uint4* gv16 = reinterpret_cast<const uint4*>(g);  // 32 uint4 per row
    const unsigned short* rb = idx + (size_t)i * 256;
    const uint4* rbw = reinterpret_cast<const uint4*>(rb);

    float acc[8] = {0.f, 0.f, 0.f, 0.f, 0.f, 0.f, 0.f, 0.f};

    auto addw = [&](uint4 w) {
        acc[0] += bf16_to_f32((unsigned short)(w.x & 0xFFFF));
        acc[1] += bf16_to_f32((unsigned short)(w.x >> 16));
        acc[2] += bf16_to_f32((unsigned short)(w.y & 0xFFFF));
        acc[3] += bf16_to_f32((unsigned short)(w.y >> 16));
        acc[4] += bf16_to_f32((unsigned short)(w.z & 0xFFFF));
        acc[5] += bf16_to_f32((unsigned short)(w.z >> 16));
        acc[6] += bf16_to_f32((unsigned short)(w.w & 0xFFFF));
        acc[7] += bf16_to_f32((unsigned short)(w.w >> 16));
    };

    int p = 0;
    // main loop: 8 indices (4 row-pairs) per iteration, 4 paired loads in flight
    uint4 iw = (c >= 8) ? rbw[0] : make_uint4(0, 0, 0, 0);
    for (; p + 8 <= c; p += 8) {
        uint4 iw_next;
        if (p + 16 <= c) iw_next = rbw[(p >> 3) + 1];
        const int j0 = iw.x & 0xFFFF, j1 = iw.x >> 16;
        const int j2 = iw.y & 0xFFFF, j3 = iw.y >> 16;
        const int j4 = iw.z & 0xFFFF, j5 = iw.z >> 16;
        const int j6 = iw.w & 0xFFFF, j7 = iw.w >> 16;
        // each lane picks its half's row (one v_cndmask; both wave-uniform)
        const int ja = half ? j1 : j0;
        const int jb = half ? j3 : j2;
        const int jc = half ? j5 : j4;
        const int jd = half ? j7 : j6;
        uint4 wa = gv16[(size_t)ja * 32 + fl];
        uint4 wb = gv16[(size_t)jb * 32 + fl];
        uint4 wc = gv16[(size_t)jc * 32 + fl];
        uint4 wd = gv16[(size_t)jd * 32 + fl];
        addw(wa); addw(wb); addw(wc); addw(wd);
        iw = iw_next;
    }
    // pair tail
    for (; p + 2 <= c; p += 2) {
        const int j0 = rb[p], j1 = rb[p + 1];
        const int jj = half ? j1 : j0;
        addw(gv16[(size_t)jj * 32 + fl]);
    }
    // odd tail: only half 0 accumulates the last row
    if (p < c) {
        const int j = rb[p];
        if (half == 0) addw(gv16[(size_t)j * 32 + fl]);
    }

    // merge halves: lane l <-> l^32 hold the same feature block
    #pragma unroll
    for (int k = 0; k < 8; ++k) acc[k] += __shfl_xor(acc[k], 32);

    // store: lane (half,fl) writes features 8*fl + 4*half .. +4 (64 x 16 B = 1 KB)
    nfloat4 r;
    r.x = acc[4 * half + 0]; r.y = acc[4 * half + 1];
    r.z = acc[4 * half + 2]; r.w = acc[4 * half + 3];
    nfloat4* outv = reinterpret_cast<nfloat4*>(h_out + (size_t)i * 256);
    __builtin_nontemporal_store(r, &outv[fl * 2 + half]);
}

extern "C" void kernel_launch(void* const* d_in, const int* in_sizes, int n_in,
                              void* d_out, int out_size, void* d_ws, size_t ws_size,
                              hipStream_t stream) {
    const float* A  = (const float*)d_in[0];   // [N, N]
    const float* h  = (const float*)d_in[1];   // [N, D]
    const float* W1 = (const float*)d_in[2];   // [D, H]
    const float* b1 = (const float*)d_in[3];   // [H]
    const float* W2 = (const float*)d_in[4];   // [H, 1]
    const float* b2 = (const float*)d_in[5];   // [1]

    const int H = in_sizes[3];                 // 64
    const int D = in_sizes[2] / H;             // 256
    const int N = in_sizes[1] / D;             // 8192

    float* out   = (float*)d_out;
    float* h_out = out;                        // N*D
    float* e_out = out + (size_t)N * D;        // N

    unsigned char* ws = (unsigned char*)d_ws;
    unsigned short* g_buf   = (unsigned short*)ws;                         // 4 MB
    unsigned short* idx_buf = (unsigned short*)(ws + (size_t)N * D * 2);   // 4 MB
    int*            cnt_buf = (int*)(ws + (size_t)N * D * 4);              // 32 KB

    scan_kernel<<<(N + 3) / 4, 256, 0, stream>>>(A, idx_buf, cnt_buf, N);
    gate_kernel<<<(N + 31) / 32, 256, 0, stream>>>(h, W1, b1, W2, b2, e_out, g_buf, N);
    gather_kernel<<<(N + 3) / 4, 256, 0, stream>>>(idx_buf, cnt_buf, g_buf, h_out, N);
}